// Round 4
// baseline (240.085 us; speedup 1.0000x reference)
//
#include <hip/hip_runtime.h>
#include <stdint.h>

// IDCT (DCT-III, DREAMPlace scaling) via even/odd split, fully fused:
//   E[m][p] = sum_{n even} x[m][n]*c(n,p),  O[m][p] = sum_{n odd} ...,
//   out[p] = E+O, out[N-1-p] = E-O   (c(n,N-1-p) = (-1)^n c(n,p)).
// R4: block tile 128m x 64p (was 128x128) -> grid 1024 = 4 blocks/CU capacity,
// targeting 3 resident blocks/CU (m97-like oversubscription). LDS 24 KB,
// dual accumulators 4x2 per wave per GEMM.
// ws: [0,32MB) A' bf16 (even cols | odd cols), [32,40) Ce, [40,48) Co.

#define Md 4096
#define Nfull 4096
#define Ph 2048   // half output width
#define Kh 2048   // half reduction
#define BM 128
#define BN 64
#define BK 32

typedef short bf16x8 __attribute__((ext_vector_type(8)));
typedef float floatx4 __attribute__((ext_vector_type(4)));
typedef unsigned short ushort_t;

__device__ __forceinline__ ushort_t f2bf(float f) {
  union { float f; uint32_t u; } v; v.f = f;
  uint32_t u = v.u;
  return (ushort_t)((u + 0x7fffu + ((u >> 16) & 1u)) >> 16);
}

// blocks [0,8192): x fp32 -> bf16 even/odd column deinterleave.
// blocks [8192,12288): fill Ce[p][ne]=c(2ne,p), Co[p][no]=c(2no+1,p).
__global__ __launch_bounds__(256) void prep_kernel(const float* __restrict__ x,
                                                   ushort_t* __restrict__ A,
                                                   ushort_t* __restrict__ Ce,
                                                   ushort_t* __restrict__ Co) {
  int b = blockIdx.x;
  if (b < 8192) {
    int i = (b * 256 + threadIdx.x) * 8;
    int m = i >> 12;
    int j = i & 4095;
    float4 a = *(const float4*)(x + i);
    float4 c = *(const float4*)(x + i + 4);
    union { ushort_t us[4]; int2 v; } ev, od;
    ev.us[0] = f2bf(a.x); od.us[0] = f2bf(a.y);
    ev.us[1] = f2bf(a.z); od.us[1] = f2bf(a.w);
    ev.us[2] = f2bf(c.x); od.us[2] = f2bf(c.y);
    ev.us[3] = f2bf(c.z); od.us[3] = f2bf(c.w);
    int half = j >> 1;
    *(int2*)(A + m * Nfull + half) = ev.v;
    *(int2*)(A + m * Nfull + Ph + half) = od.v;
  } else {
    int idx = ((b - 8192) * 256 + threadIdx.x) * 8;  // [0, 8M)
    const float s = 3.14159265358979f / 8192.0f;     // pi/(2N)
    union { ushort_t us[8]; int4 v; } pk;
    if (idx < Ph * Kh) {               // Ce
      int p = idx >> 11;
      int ne0 = idx & 2047;
      int tp = 2 * p + 1;
#pragma unroll
      for (int jj = 0; jj < 8; ++jj) {
        int n = 2 * (ne0 + jj);
        int t = (n * tp) & 16383;      // mod 4N: exact int reduction
        float c = (n == 0) ? 1.0f : 2.0f * __cosf(s * (float)t);
        pk.us[jj] = f2bf(c);
      }
      *(int4*)(Ce + idx) = pk.v;
    } else {                           // Co
      int local = idx - Ph * Kh;
      int p = local >> 11;
      int no0 = local & 2047;
      int tp = 2 * p + 1;
#pragma unroll
      for (int jj = 0; jj < 8; ++jj) {
        int n = 2 * (no0 + jj) + 1;
        int t = (n * tp) & 16383;
        pk.us[jj] = f2bf(2.0f * __cosf(s * (float)t));
      }
      *(int4*)(Co + local) = pk.v;
    }
  }
}

// Fused dual GEMM + butterfly. Block tile: 128 rows (m) x 64 cols (p).
// 4 waves in 2x2: wave tile 64m x 32p per GEMM; frags 4(m) x 2(p), dual
// accumulator sets E/O (64 acc VGPRs). K=2048, BK=32 -> 64 iters,
// 16 MFMAs + 12 ds_read_b128 per wave per iter.
// __launch_bounds__(256,3): 3 waves/EU -> 3 blocks/CU target, VGPR cap 170.
__global__ __launch_bounds__(256, 3) void gemm_fused(const ushort_t* __restrict__ A,
                                                     const ushort_t* __restrict__ Ce,
                                                     const ushort_t* __restrict__ Co,
                                                     float* __restrict__ out) {
  // Linear tile order (row-major, 64B rows) — REQUIRED by global_load_lds
  // (wave-uniform base + lane*16B), so no bank-conflict padding possible.
  __shared__ __align__(16) ushort_t AsE[BM * BK];   // 8 KB
  __shared__ __align__(16) ushort_t AsO[BM * BK];   // 8 KB
  __shared__ __align__(16) ushort_t BsE[BN * BK];   // 4 KB
  __shared__ __align__(16) ushort_t BsO[BN * BK];   // 4 KB

  const int tid = threadIdx.x;
  const int wid = tid >> 6;
  const int lane = tid & 63;

  const int bm = blockIdx.y * BM;
  const int bn = blockIdx.x * BN;

  const int wm = (wid & 1) * 64;   // wave m-offset
  const int wn = (wid >> 1) * 32;  // wave p-offset

  const int lrow = lane & 15;
  const int kq = (lane >> 4) * 8;

  floatx4 accE[4][2] = {};
  floatx4 accO[4][2] = {};

  // staging: A tile = 128 rows x 64B = 8 KB -> 2 issues of 256 thr x 16B;
  //          B tile = 64 rows x 64B = 4 KB -> 1 issue.
  // chunk c: row=c>>2, elem=(c&3)*8; LDS elem offset = 8c (linear order).
  const int r0 = tid >> 2, e0 = (tid & 3) * 8;
  const int r1 = r0 + 64;
  const int l0 = wid * 512;            // wave-uniform LDS base (elements)
  const int l1 = 2048 + wid * 512;

  const ushort_t* Ae = A + (size_t)bm * Nfull;        // even half, row stride 4096
  const ushort_t* Ao = Ae + Ph;                       // odd half
  const ushort_t* Be = Ce + (size_t)bn * Kh;          // row stride 2048
  const ushort_t* Bo = Co + (size_t)bn * Kh;

#define GLDS(src, dst) __builtin_amdgcn_global_load_lds( \
      (const __attribute__((address_space(1))) void*)(src), \
      (__attribute__((address_space(3))) void*)(dst), 16, 0, 0)

  for (int k0 = 0; k0 < Kh; k0 += BK) {
    GLDS(Ae + (size_t)r0 * Nfull + k0 + e0, AsE + l0);
    GLDS(Ae + (size_t)r1 * Nfull + k0 + e0, AsE + l1);
    GLDS(Ao + (size_t)r0 * Nfull + k0 + e0, AsO + l0);
    GLDS(Ao + (size_t)r1 * Nfull + k0 + e0, AsO + l1);
    GLDS(Be + (size_t)r0 * Kh + k0 + e0, BsE + l0);
    GLDS(Bo + (size_t)r0 * Kh + k0 + e0, BsO + l0);
    __syncthreads();   // drains vmcnt -> staging visible

    bf16x8 bE[2], bO[2];
#pragma unroll
    for (int f = 0; f < 2; ++f) {
      bE[f] = *(const bf16x8*)(BsE + (wn + f * 16 + lrow) * BK + kq);
      bO[f] = *(const bf16x8*)(BsO + (wn + f * 16 + lrow) * BK + kq);
    }
#pragma unroll
    for (int im = 0; im < 4; ++im) {
      bf16x8 aE = *(const bf16x8*)(AsE + (wm + im * 16 + lrow) * BK + kq);
      bf16x8 aO = *(const bf16x8*)(AsO + (wm + im * 16 + lrow) * BK + kq);
#pragma unroll
      for (int jn = 0; jn < 2; ++jn) {
        accE[im][jn] = __builtin_amdgcn_mfma_f32_16x16x32_bf16(aE, bE[jn], accE[im][jn], 0, 0, 0);
        accO[im][jn] = __builtin_amdgcn_mfma_f32_16x16x32_bf16(aO, bO[jn], accO[im][jn], 0, 0, 0);
      }
    }
    __syncthreads();   // all waves done reading before next overwrite
  }
#undef GLDS

  // Epilogue butterfly. C/D mapping: col=lane&15, row=(lane>>4)*4+r.
#pragma unroll
  for (int im = 0; im < 4; ++im) {
    int rb = bm + wm + im * 16 + (lane >> 4) * 4;
#pragma unroll
    for (int jn = 0; jn < 2; ++jn) {
      int p = bn + wn + jn * 16 + lrow;
      float* lo = out + (size_t)rb * Nfull + p;
      float* hi = out + (size_t)rb * Nfull + (Nfull - 1 - p);
#pragma unroll
      for (int r = 0; r < 4; ++r) {
        float e = accE[im][jn][r];
        float o = accO[im][jn][r];
        lo[(size_t)r * Nfull] = e + o;
        hi[(size_t)r * Nfull] = e - o;
      }
    }
  }
}

extern "C" void kernel_launch(void* const* d_in, const int* in_sizes, int n_in,
                              void* d_out, int out_size, void* d_ws, size_t ws_size,
                              hipStream_t stream) {
  const float* x = (const float*)d_in[0];
  float* out = (float*)d_out;
  ushort_t* Axb = (ushort_t*)d_ws;                     // 32 MB
  ushort_t* Ce = Axb + (size_t)Md * Nfull;             // 8 MB
  ushort_t* Co = Ce + (size_t)Ph * Kh;                 // 8 MB

  prep_kernel<<<12288, 256, 0, stream>>>(x, Axb, Ce, Co);

  dim3 grid(Ph / BN, Md / BM);  // 32 x 32 = 1024 blocks = 4/CU capacity
  gemm_fused<<<grid, 256, 0, stream>>>(Axb, Ce, Co, out);
}

// Round 5
// 194.947 us; speedup vs baseline: 1.2315x; 1.2315x over previous
//
#include <hip/hip_runtime.h>
#include <stdint.h>

// IDCT (DCT-III, DREAMPlace scaling) via even/odd split, fully fused:
//   E[m][p] = sum_{n even} x[m][n]*c(n,p),  O[m][p] = sum_{n odd} ...,
//   out[p] = E+O, out[N-1-p] = E-O   (c(n,N-1-p) = (-1)^n c(n,p)).
// R5: back to the R3 128x128 fused tile (R4's 128x64 regressed: barrier
// events doubled while MFMA-per-barrier halved). New: BK=64 -> 32 K-iters
// instead of 64, halving barrier-drain events; 64 KB LDS still gives the
// same 2 blocks/CU the 512-block grid can use.
// ws: [0,32MB) A' bf16 (even cols | odd cols), [32,40) Ce, [40,48) Co.

#define Md 4096
#define Nfull 4096
#define Ph 2048   // half output width
#define Kh 2048   // half reduction
#define BM 128
#define BN 128
#define BK 64

typedef short bf16x8 __attribute__((ext_vector_type(8)));
typedef float floatx4 __attribute__((ext_vector_type(4)));
typedef unsigned short ushort_t;

__device__ __forceinline__ ushort_t f2bf(float f) {
  union { float f; uint32_t u; } v; v.f = f;
  uint32_t u = v.u;
  return (ushort_t)((u + 0x7fffu + ((u >> 16) & 1u)) >> 16);
}

// blocks [0,8192): x fp32 -> bf16 even/odd column deinterleave.
// blocks [8192,12288): fill Ce[p][ne]=c(2ne,p), Co[p][no]=c(2no+1,p).
__global__ __launch_bounds__(256) void prep_kernel(const float* __restrict__ x,
                                                   ushort_t* __restrict__ A,
                                                   ushort_t* __restrict__ Ce,
                                                   ushort_t* __restrict__ Co) {
  int b = blockIdx.x;
  if (b < 8192) {
    int i = (b * 256 + threadIdx.x) * 8;
    int m = i >> 12;
    int j = i & 4095;
    float4 a = *(const float4*)(x + i);
    float4 c = *(const float4*)(x + i + 4);
    union { ushort_t us[4]; int2 v; } ev, od;
    ev.us[0] = f2bf(a.x); od.us[0] = f2bf(a.y);
    ev.us[1] = f2bf(a.z); od.us[1] = f2bf(a.w);
    ev.us[2] = f2bf(c.x); od.us[2] = f2bf(c.y);
    ev.us[3] = f2bf(c.z); od.us[3] = f2bf(c.w);
    int half = j >> 1;
    *(int2*)(A + m * Nfull + half) = ev.v;
    *(int2*)(A + m * Nfull + Ph + half) = od.v;
  } else {
    int idx = ((b - 8192) * 256 + threadIdx.x) * 8;  // [0, 8M)
    const float s = 3.14159265358979f / 8192.0f;     // pi/(2N)
    union { ushort_t us[8]; int4 v; } pk;
    if (idx < Ph * Kh) {               // Ce
      int p = idx >> 11;
      int ne0 = idx & 2047;
      int tp = 2 * p + 1;
#pragma unroll
      for (int jj = 0; jj < 8; ++jj) {
        int n = 2 * (ne0 + jj);
        int t = (n * tp) & 16383;      // mod 4N: exact int reduction
        float c = (n == 0) ? 1.0f : 2.0f * __cosf(s * (float)t);
        pk.us[jj] = f2bf(c);
      }
      *(int4*)(Ce + idx) = pk.v;
    } else {                           // Co
      int local = idx - Ph * Kh;
      int p = local >> 11;
      int no0 = local & 2047;
      int tp = 2 * p + 1;
#pragma unroll
      for (int jj = 0; jj < 8; ++jj) {
        int n = 2 * (no0 + jj) + 1;
        int t = (n * tp) & 16383;
        pk.us[jj] = f2bf(2.0f * __cosf(s * (float)t));
      }
      *(int4*)(Co + local) = pk.v;
    }
  }
}

// Fused dual GEMM + butterfly. Block tile 128m x 128p, BK=64.
// 4 waves 2x2: wave tile 64m x 64p per GEMM, frags 4x4, dual acc E/O
// (128 acc VGPRs). 32 K-iters; per wave-iter: 32 ds_read_b128 + 64 MFMAs,
// 16 global_load_lds_dwordx4 staging issues per block-iter.
__global__ __launch_bounds__(256, 2) void gemm_fused(const ushort_t* __restrict__ A,
                                                     const ushort_t* __restrict__ Ce,
                                                     const ushort_t* __restrict__ Co,
                                                     float* __restrict__ out) {
  // Linear tile order (row-major, 128B rows) — REQUIRED by global_load_lds
  // (wave-uniform base + lane*16B scatter), so no padding possible.
  __shared__ __align__(16) ushort_t AsE[BM * BK];   // 16 KB
  __shared__ __align__(16) ushort_t AsO[BM * BK];   // 16 KB
  __shared__ __align__(16) ushort_t BsE[BN * BK];   // 16 KB
  __shared__ __align__(16) ushort_t BsO[BN * BK];   // 16 KB  -> 64 KB total

  const int tid = threadIdx.x;
  const int wid = tid >> 6;
  const int lane = tid & 63;

  const int bm = blockIdx.y * BM;
  const int bn = blockIdx.x * BN;

  const int wm = (wid & 1) * 64;
  const int wn = (wid >> 1) * 64;

  const int lrow = lane & 15;
  const int kq = (lane >> 4) * 8;

  floatx4 accE[4][4] = {};
  floatx4 accO[4][4] = {};

  // Staging: tile = 128 rows x 128B = 16 KB -> 4 issues of 256 thr x 16B.
  // chunk c = i*256+tid: row = c>>3 = i*32 + (tid>>3), colgrp = tid&7,
  // LDS elem offset = 8c. Wave-uniform LDS base per (issue, wave).
  const int rr = tid >> 3;             // 0..31
  const int ee = (tid & 7) * 8;        // element offset within row
  const int lb = wid * 512;            // 8 * wid*64

  const ushort_t* Ae = A + (size_t)bm * Nfull;        // even half, row stride 4096
  const ushort_t* Ao = Ae + Ph;                       // odd half
  const ushort_t* Be = Ce + (size_t)bn * Kh;          // row stride 2048
  const ushort_t* Bo = Co + (size_t)bn * Kh;

#define GLDS(src, dst) __builtin_amdgcn_global_load_lds( \
      (const __attribute__((address_space(1))) void*)(src), \
      (__attribute__((address_space(3))) void*)(dst), 16, 0, 0)

  for (int k0 = 0; k0 < Kh; k0 += BK) {
#pragma unroll
    for (int i = 0; i < 4; ++i) {      // 4 issues per matrix
      int r = i * 32 + rr;
      int l = i * 2048 + lb;
      GLDS(Ae + (size_t)r * Nfull + k0 + ee, AsE + l);
      GLDS(Ao + (size_t)r * Nfull + k0 + ee, AsO + l);
      GLDS(Be + (size_t)r * Kh   + k0 + ee, BsE + l);
      GLDS(Bo + (size_t)r * Kh   + k0 + ee, BsO + l);
    }
    __syncthreads();   // drains vmcnt -> staging visible

#pragma unroll
    for (int kk = 0; kk < 2; ++kk) {   // two K=32 sub-steps
      const int ko = kk * 32 + kq;
      bf16x8 bE[4], bO[4];
#pragma unroll
      for (int f = 0; f < 4; ++f) {
        bE[f] = *(const bf16x8*)(BsE + (wn + f * 16 + lrow) * BK + ko);
        bO[f] = *(const bf16x8*)(BsO + (wn + f * 16 + lrow) * BK + ko);
      }
#pragma unroll
      for (int im = 0; im < 4; ++im) {
        bf16x8 aE = *(const bf16x8*)(AsE + (wm + im * 16 + lrow) * BK + ko);
        bf16x8 aO = *(const bf16x8*)(AsO + (wm + im * 16 + lrow) * BK + ko);
#pragma unroll
        for (int jn = 0; jn < 4; ++jn) {
          accE[im][jn] = __builtin_amdgcn_mfma_f32_16x16x32_bf16(aE, bE[jn], accE[im][jn], 0, 0, 0);
          accO[im][jn] = __builtin_amdgcn_mfma_f32_16x16x32_bf16(aO, bO[jn], accO[im][jn], 0, 0, 0);
        }
      }
    }
    __syncthreads();   // all waves done reading before next overwrite
  }
#undef GLDS

  // Epilogue butterfly. C/D mapping: col=lane&15, row=(lane>>4)*4+r.
#pragma unroll
  for (int im = 0; im < 4; ++im) {
    int rb = bm + wm + im * 16 + (lane >> 4) * 4;
#pragma unroll
    for (int jn = 0; jn < 4; ++jn) {
      int p = bn + wn + jn * 16 + lrow;
      float* lo = out + (size_t)rb * Nfull + p;
      float* hi = out + (size_t)rb * Nfull + (Nfull - 1 - p);
#pragma unroll
      for (int r = 0; r < 4; ++r) {
        float e = accE[im][jn][r];
        float o = accO[im][jn][r];
        lo[(size_t)r * Nfull] = e + o;
        hi[(size_t)r * Nfull] = e - o;
      }
    }
  }
}

extern "C" void kernel_launch(void* const* d_in, const int* in_sizes, int n_in,
                              void* d_out, int out_size, void* d_ws, size_t ws_size,
                              hipStream_t stream) {
  const float* x = (const float*)d_in[0];
  float* out = (float*)d_out;
  ushort_t* Axb = (ushort_t*)d_ws;                     // 32 MB
  ushort_t* Ce = Axb + (size_t)Md * Nfull;             // 8 MB
  ushort_t* Co = Ce + (size_t)Ph * Kh;                 // 8 MB

  prep_kernel<<<12288, 256, 0, stream>>>(x, Axb, Ce, Co);

  dim3 grid(Ph / BN, Md / BM);  // 16 x 32 = 512 blocks = 2/CU
  gemm_fused<<<grid, 256, 0, stream>>>(Axb, Ce, Co, out);
}